// Round 14
// baseline (43.358 us; speedup 1.0000x reference)
//
#include <hip/hip_runtime.h>
#include <math.h>

#define BB 32
#define LL 2048
#define DD 256
#define NC 16
#define TPB 256    // gather kernels: 4 waves
#define TPR 1024   // reduce kernels: 16 waves

#define SPLIT 32                        // proven sweet spot
#define NBLK  (BB * SPLIT)              // 1024 blocks
#define TOK_CHUNK (LL / SPLIT)          // 64 tokens per block
#define TOK_WAVE  (TOK_CHUNK / 4)       // 16 tokens per wave — all in flight

// ws layout (floats):
//  emb  [BB][LL][DD]    masked embedding rows, streamed by pass A   (64 MB)
//  pes  [BB][SPLIT][DD] partial emb_sum (transposed for contiguous reduce)
//  plen [BB][SPLIT]
//  pout [BB][SPLIT][DD]
//  pys  [BB][SPLIT]
//  emb_sum [BB][DD] | lens [BB]

__global__ __launch_bounds__(TPB) void kA_partial(
    const int* __restrict__ idx, const float* __restrict__ mask,
    const float4* __restrict__ enc4, float4* __restrict__ emb4,
    float* __restrict__ pes, float* __restrict__ plen) {
  const int b     = blockIdx.x / SPLIT;
  const int chunk = blockIdx.x % SPLIT;
  const int wave  = threadIdx.x >> 6;
  const int lane  = threadIdx.x & 63;
  const int tid   = threadIdx.x;
  const int l0 = chunk * TOK_CHUNK + wave * TOK_WAVE;

  int   id_r[TOK_WAVE];
  float m_r[TOK_WAVE];
  #pragma unroll
  for (int t = 0; t < TOK_WAVE; ++t) {
    id_r[t] = idx[b * LL + l0 + t];
    m_r[t]  = mask[b * LL + l0 + t];
  }
  float4 v_r[TOK_WAVE];                 // all 16 gathers in flight
  #pragma unroll
  for (int t = 0; t < TOK_WAVE; ++t)
    v_r[t] = enc4[(size_t)id_r[t] * (DD / 4) + lane];

  float4 acc = {0.f, 0.f, 0.f, 0.f};
  float lenacc = 0.f;
  #pragma unroll
  for (int t = 0; t < TOK_WAVE; ++t) {
    const float m = m_r[t];
    float4 w;
    w.x = v_r[t].x * m; w.y = v_r[t].y * m;
    w.z = v_r[t].z * m; w.w = v_r[t].w * m;
    // stream the masked row out: 64 lanes x 16B = 1KB contiguous per token
    emb4[(size_t)(b * LL + l0 + t) * (DD / 4) + lane] = w;
    acc.x += w.x; acc.y += w.y; acc.z += w.z; acc.w += w.w;
    lenacc += m;
  }

  __shared__ float lds[4][DD];
  __shared__ float llds[4];
  lds[wave][lane * 4 + 0] = acc.x;
  lds[wave][lane * 4 + 1] = acc.y;
  lds[wave][lane * 4 + 2] = acc.z;
  lds[wave][lane * 4 + 3] = acc.w;
  if (lane == 0) llds[wave] = lenacc;
  __syncthreads();

  const float s = lds[0][tid] + lds[1][tid] + lds[2][tid] + lds[3][tid];
  pes[(b * SPLIT + chunk) * DD + tid] = s;                 // transposed layout
  if (tid == 0) plen[b * SPLIT + chunk] = llds[0] + llds[1] + llds[2] + llds[3];
}

__global__ __launch_bounds__(TPR) void kR1(
    const float* __restrict__ pes, const float* __restrict__ plen,
    float* __restrict__ emb_sum, float* __restrict__ lens) {
  const int b   = blockIdx.x;
  const int tid = threadIdx.x;
  const int q   = tid >> 8;       // 0..3
  const int d   = tid & 255;

  float s = 0.f;
  #pragma unroll
  for (int c = q * 8; c < q * 8 + 8; ++c)
    s += pes[(b * SPLIT + c) * DD + d];   // contiguous 32KB span per block

  __shared__ float red[4][DD];
  red[q][d] = s;

  if (tid < 64) {
    float lv = (tid < SPLIT) ? plen[b * SPLIT + tid] : 0.f;
    #pragma unroll
    for (int off = 32; off > 0; off >>= 1) lv += __shfl_xor(lv, off);
    if (tid == 0) lens[b] = lv;
  }
  __syncthreads();
  if (q == 0) emb_sum[b * DD + d] = red[0][d] + red[1][d] + red[2][d] + red[3][d];
}

__global__ __launch_bounds__(TPB) void kB_seq(
    const float* __restrict__ mask, const float4* __restrict__ emb4,
    const float* __restrict__ emb_sum,
    float* __restrict__ pout, float* __restrict__ pys) {
  const int b     = blockIdx.x / SPLIT;
  const int chunk = blockIdx.x % SPLIT;
  const int wave  = threadIdx.x >> 6;
  const int lane  = threadIdx.x & 63;
  const int tid   = threadIdx.x;
  const int l0 = chunk * TOK_CHUNK + wave * TOK_WAVE;

  __shared__ __align__(16) float esb[DD];
  esb[tid] = emb_sum[b * DD + tid];
  __syncthreads();
  const float4 es = *reinterpret_cast<const float4*>(&esb[lane * 4]);

  float m_r[TOK_WAVE];
  #pragma unroll
  for (int t = 0; t < TOK_WAVE; ++t)
    m_r[t] = mask[b * LL + l0 + t];

  // sequential, fully-coalesced reads of the masked rows (L3-resident)
  const float4* erow = emb4 + (size_t)(b * LL + l0) * (DD / 4);
  float4 v_r[TOK_WAVE];                 // all 16 reads in flight
  #pragma unroll
  for (int t = 0; t < TOK_WAVE; ++t)
    v_r[t] = erow[(size_t)t * (DD / 4) + lane];

  float4 acc = {0.f, 0.f, 0.f, 0.f};
  float ys = 0.f;
  #pragma unroll
  for (int t = 0; t < TOK_WAVE; ++t) {
    const float4 w = v_r[t];            // already masked: w = m * row
    float d = w.x * es.x + w.y * es.y + w.z * es.z + w.w * es.w;
    #pragma unroll
    for (int off = 32; off > 0; off >>= 1) d += __shfl_xor(d, off);
    const float y = expf(d) * m_r[t];   // score = emb_l . emb_sum ; y = exp*mask
    acc.x += y * w.x; acc.y += y * w.y;
    acc.z += y * w.z; acc.w += y * w.w;
    ys += y;                            // identical across lanes
  }

  __shared__ float lds[4][DD];
  __shared__ float ylds[4];
  lds[wave][lane * 4 + 0] = acc.x;
  lds[wave][lane * 4 + 1] = acc.y;
  lds[wave][lane * 4 + 2] = acc.z;
  lds[wave][lane * 4 + 3] = acc.w;
  if (lane == 0) ylds[wave] = ys;
  __syncthreads();

  const float s = lds[0][tid] + lds[1][tid] + lds[2][tid] + lds[3][tid];
  pout[(b * SPLIT + chunk) * DD + tid] = s;                // transposed layout
  if (tid == 0) pys[b * SPLIT + chunk] = ylds[0] + ylds[1] + ylds[2] + ylds[3];
}

__global__ __launch_bounds__(TPR) void kR2head(
    const float* __restrict__ pout, const float* __restrict__ pys,
    const float* __restrict__ emb_sum, const float* __restrict__ lens,
    const float* __restrict__ dec_w, float* __restrict__ out) {
  const int b   = blockIdx.x;
  const int tid = threadIdx.x;
  const int q   = tid >> 8;       // 0..3
  const int d   = tid & 255;

  float s = 0.f;
  #pragma unroll
  for (int c = q * 8; c < q * 8 + 8; ++c)
    s += pout[(b * SPLIT + c) * DD + d];  // contiguous 32KB span

  __shared__ float red[4][DD];
  __shared__ __align__(16) float vec[DD];
  __shared__ float ysum_s;
  red[q][d] = s;

  if (tid < 64) {
    float v = (tid < SPLIT) ? pys[b * SPLIT + tid] : 0.f;
    #pragma unroll
    for (int off = 32; off > 0; off >>= 1) v += __shfl_xor(v, off);
    if (tid == 0) ysum_s = v;
  }
  __syncthreads();

  if (q == 0) {
    const float os = red[0][d] + red[1][d] + red[2][d] + red[3][d];
    vec[d] = os / ysum_s + emb_sum[b * DD + d] / lens[b];
  }
  __syncthreads();

  // head: 16 waves, one class per wave
  const int wave = tid >> 6;      // 0..15 == class
  const int lane = tid & 63;
  const float4 vv = *reinterpret_cast<const float4*>(&vec[lane * 4]);
  const float4 dw = reinterpret_cast<const float4*>(dec_w)[wave * (DD / 4) + lane];
  float dsum = vv.x * dw.x + vv.y * dw.y + vv.z * dw.z + vv.w * dw.w;
  #pragma unroll
  for (int off = 32; off > 0; off >>= 1) dsum += __shfl_xor(dsum, off);
  if (lane == 0) out[b * NC + wave] = dsum;
}

extern "C" void kernel_launch(void* const* d_in, const int* in_sizes, int n_in,
                              void* d_out, int out_size, void* d_ws, size_t ws_size,
                              hipStream_t stream) {
  const int*    idx   = (const int*)d_in[0];
  const float*  mask  = (const float*)d_in[1];
  const float4* enc4  = (const float4*)d_in[2];
  const float*  dec_w = (const float*)d_in[3];
  float* out = (float*)d_out;

  float* ws = (float*)d_ws;
  float* emb     = ws;                        // BB*LL*DD  (64 MB)
  float* pes     = emb + (size_t)BB * LL * DD;
  float* plen    = pes + BB * SPLIT * DD;
  float* pout    = plen + BB * SPLIT;
  float* pys     = pout + BB * SPLIT * DD;
  float* emb_sum = pys + BB * SPLIT;
  float* lens    = emb_sum + BB * DD;

  hipLaunchKernelGGL(kA_partial, dim3(NBLK), dim3(TPB), 0, stream,
                     idx, mask, enc4, (float4*)emb, pes, plen);
  hipLaunchKernelGGL(kR1, dim3(BB), dim3(TPR), 0, stream, pes, plen, emb_sum, lens);
  hipLaunchKernelGGL(kB_seq, dim3(NBLK), dim3(TPB), 0, stream,
                     mask, (const float4*)emb, emb_sum, pout, pys);
  hipLaunchKernelGGL(kR2head, dim3(BB), dim3(TPR), 0, stream,
                     pout, pys, emb_sum, lens, dec_w, out);
}

// Round 15
// 31.303 us; speedup vs baseline: 1.3851x; 1.3851x over previous
//
#include <hip/hip_runtime.h>
#include <math.h>

#define BB 32
#define LL 2048
#define DD 256
#define NC 16
#define TPB 256    // gather kernels: 4 waves
#define TPR 1024   // reduce kernels: 16 waves

#define SPLIT 32                        // proven sweet spot
#define NBLK  (BB * SPLIT)              // 1024 blocks
#define TOK_CHUNK (LL / SPLIT)          // 64 tokens per block
#define TOK_WAVE  (TOK_CHUNK / 4)       // 16 tokens per wave — all in flight

// ws layout (floats), partials TRANSPOSED to [b][chunk][d] for contiguous reduce reads:
//  pes  [BB][SPLIT][DD] | plen [BB][SPLIT] | pout [BB][SPLIT][DD] | pys [BB][SPLIT]
//  emb_sum [BB][DD] | lens [BB]

__global__ __launch_bounds__(TPB) void kA_partial(
    const int* __restrict__ idx, const float* __restrict__ mask,
    const float4* __restrict__ enc4,
    float* __restrict__ pes, float* __restrict__ plen) {
  const int b     = blockIdx.x / SPLIT;
  const int chunk = blockIdx.x % SPLIT;
  const int wave  = threadIdx.x >> 6;
  const int lane  = threadIdx.x & 63;
  const int tid   = threadIdx.x;
  const int l0 = chunk * TOK_CHUNK + wave * TOK_WAVE;

  int   id_r[TOK_WAVE];
  float m_r[TOK_WAVE];
  #pragma unroll
  for (int t = 0; t < TOK_WAVE; ++t) {
    id_r[t] = idx[b * LL + l0 + t];
    m_r[t]  = mask[b * LL + l0 + t];
  }
  float4 v_r[TOK_WAVE];                 // all 16 gathers in flight
  #pragma unroll
  for (int t = 0; t < TOK_WAVE; ++t)
    v_r[t] = enc4[(size_t)id_r[t] * (DD / 4) + lane];

  float4 acc = {0.f, 0.f, 0.f, 0.f};
  float lenacc = 0.f;
  #pragma unroll
  for (int t = 0; t < TOK_WAVE; ++t) {
    const float m = m_r[t];
    acc.x += v_r[t].x * m; acc.y += v_r[t].y * m;
    acc.z += v_r[t].z * m; acc.w += v_r[t].w * m;
    lenacc += m;
  }

  __shared__ float lds[4][DD];
  __shared__ float llds[4];
  lds[wave][lane * 4 + 0] = acc.x;
  lds[wave][lane * 4 + 1] = acc.y;
  lds[wave][lane * 4 + 2] = acc.z;
  lds[wave][lane * 4 + 3] = acc.w;
  if (lane == 0) llds[wave] = lenacc;
  __syncthreads();

  const float s = lds[0][tid] + lds[1][tid] + lds[2][tid] + lds[3][tid];
  pes[(b * SPLIT + chunk) * DD + tid] = s;                 // transposed layout
  if (tid == 0) plen[b * SPLIT + chunk] = llds[0] + llds[1] + llds[2] + llds[3];
}

__global__ __launch_bounds__(TPR) void kR1(
    const float* __restrict__ pes, const float* __restrict__ plen,
    float* __restrict__ emb_sum, float* __restrict__ lens) {
  const int b   = blockIdx.x;
  const int tid = threadIdx.x;
  const int q   = tid >> 8;       // 0..3
  const int d   = tid & 255;

  float s = 0.f;
  #pragma unroll
  for (int c = q * 8; c < q * 8 + 8; ++c)
    s += pes[(b * SPLIT + c) * DD + d];   // contiguous 32KB span per block

  __shared__ float red[4][DD];
  red[q][d] = s;

  if (tid < 64) {
    float lv = (tid < SPLIT) ? plen[b * SPLIT + tid] : 0.f;
    #pragma unroll
    for (int off = 32; off > 0; off >>= 1) lv += __shfl_xor(lv, off);
    if (tid == 0) lens[b] = lv;
  }
  __syncthreads();
  if (q == 0) emb_sum[b * DD + d] = red[0][d] + red[1][d] + red[2][d] + red[3][d];
}

__global__ __launch_bounds__(TPB) void kB_partial(
    const int* __restrict__ idx, const float* __restrict__ mask,
    const float4* __restrict__ enc4, const float* __restrict__ emb_sum,
    float* __restrict__ pout, float* __restrict__ pys) {
  const int b     = blockIdx.x / SPLIT;
  const int chunk = blockIdx.x % SPLIT;
  const int wave  = threadIdx.x >> 6;
  const int lane  = threadIdx.x & 63;
  const int tid   = threadIdx.x;
  const int l0 = chunk * TOK_CHUNK + wave * TOK_WAVE;

  __shared__ __align__(16) float esb[DD];
  esb[tid] = emb_sum[b * DD + tid];
  __syncthreads();
  const float4 es = *reinterpret_cast<const float4*>(&esb[lane * 4]);

  int   id_r[TOK_WAVE];
  float m_r[TOK_WAVE];
  #pragma unroll
  for (int t = 0; t < TOK_WAVE; ++t) {
    id_r[t] = idx[b * LL + l0 + t];
    m_r[t]  = mask[b * LL + l0 + t];
  }
  float4 v_r[TOK_WAVE];                 // all 16 gathers in flight
  #pragma unroll
  for (int t = 0; t < TOK_WAVE; ++t)
    v_r[t] = enc4[(size_t)id_r[t] * (DD / 4) + lane];

  float4 acc = {0.f, 0.f, 0.f, 0.f};
  float ys = 0.f;
  #pragma unroll
  for (int t = 0; t < TOK_WAVE; ++t) {
    const float m = m_r[t];
    const float4 v = v_r[t];
    float d = v.x * es.x + v.y * es.y + v.z * es.z + v.w * es.w;
    #pragma unroll
    for (int off = 32; off > 0; off >>= 1) d += __shfl_xor(d, off);
    const float score = d * m;          // emb_l . emb_sum  (emb_l = m*row)
    const float y = expf(score) * m;    // y = exp(scores) * mask
    const float ym = y * m;             // weight on raw row
    acc.x += ym * v.x; acc.y += ym * v.y;
    acc.z += ym * v.z; acc.w += ym * v.w;
    ys += y;                            // identical across lanes
  }

  __shared__ float lds[4][DD];
  __shared__ float ylds[4];
  lds[wave][lane * 4 + 0] = acc.x;
  lds[wave][lane * 4 + 1] = acc.y;
  lds[wave][lane * 4 + 2] = acc.z;
  lds[wave][lane * 4 + 3] = acc.w;
  if (lane == 0) ylds[wave] = ys;
  __syncthreads();

  const float s = lds[0][tid] + lds[1][tid] + lds[2][tid] + lds[3][tid];
  pout[(b * SPLIT + chunk) * DD + tid] = s;                // transposed layout
  if (tid == 0) pys[b * SPLIT + chunk] = ylds[0] + ylds[1] + ylds[2] + ylds[3];
}

__global__ __launch_bounds__(TPR) void kR2head(
    const float* __restrict__ pout, const float* __restrict__ pys,
    const float* __restrict__ emb_sum, const float* __restrict__ lens,
    const float* __restrict__ dec_w, float* __restrict__ out) {
  const int b   = blockIdx.x;
  const int tid = threadIdx.x;
  const int q   = tid >> 8;       // 0..3
  const int d   = tid & 255;

  float s = 0.f;
  #pragma unroll
  for (int c = q * 8; c < q * 8 + 8; ++c)
    s += pout[(b * SPLIT + c) * DD + d];  // contiguous 32KB span

  __shared__ float red[4][DD];
  __shared__ __align__(16) float vec[DD];
  __shared__ float ysum_s;
  red[q][d] = s;

  if (tid < 64) {
    float v = (tid < SPLIT) ? pys[b * SPLIT + tid] : 0.f;
    #pragma unroll
    for (int off = 32; off > 0; off >>= 1) v += __shfl_xor(v, off);
    if (tid == 0) ysum_s = v;
  }
  __syncthreads();

  if (q == 0) {
    const float os = red[0][d] + red[1][d] + red[2][d] + red[3][d];
    vec[d] = os / ysum_s + emb_sum[b * DD + d] / lens[b];
  }
  __syncthreads();

  // head: 16 waves, one class per wave
  const int wave = tid >> 6;      // 0..15 == class
  const int lane = tid & 63;
  const float4 vv = *reinterpret_cast<const float4*>(&vec[lane * 4]);
  const float4 dw = reinterpret_cast<const float4*>(dec_w)[wave * (DD / 4) + lane];
  float dsum = vv.x * dw.x + vv.y * dw.y + vv.z * dw.z + vv.w * dw.w;
  #pragma unroll
  for (int off = 32; off > 0; off >>= 1) dsum += __shfl_xor(dsum, off);
  if (lane == 0) out[b * NC + wave] = dsum;
}

extern "C" void kernel_launch(void* const* d_in, const int* in_sizes, int n_in,
                              void* d_out, int out_size, void* d_ws, size_t ws_size,
                              hipStream_t stream) {
  const int*    idx   = (const int*)d_in[0];
  const float*  mask  = (const float*)d_in[1];
  const float4* enc4  = (const float4*)d_in[2];
  const float*  dec_w = (const float*)d_in[3];
  float* out = (float*)d_out;

  float* ws = (float*)d_ws;
  float* pes     = ws;                        // BB*SPLIT*DD
  float* plen    = pes + BB * SPLIT * DD;     // BB*SPLIT
  float* pout    = plen + BB * SPLIT;         // BB*SPLIT*DD
  float* pys     = pout + BB * SPLIT * DD;    // BB*SPLIT
  float* emb_sum = pys + BB * SPLIT;          // BB*DD
  float* lens    = emb_sum + BB * DD;         // BB

  hipLaunchKernelGGL(kA_partial, dim3(NBLK), dim3(TPB), 0, stream,
                     idx, mask, enc4, pes, plen);
  hipLaunchKernelGGL(kR1, dim3(BB), dim3(TPR), 0, stream, pes, plen, emb_sum, lens);
  hipLaunchKernelGGL(kB_partial, dim3(NBLK), dim3(TPB), 0, stream,
                     idx, mask, enc4, emb_sum, pout, pys);
  hipLaunchKernelGGL(kR2head, dim3(BB), dim3(TPR), 0, stream,
                     pout, pys, emb_sum, lens, dec_w, out);
}